// Round 4
// baseline (462.092 us; speedup 1.0000x reference)
//
#include <hip/hip_runtime.h>
#include <hip/hip_fp16.h>
#include <math.h>

// Problem constants
#define BB 8
#define SS 8192
#define DD 512
#define HH 256
#define MM (BB * SS)        // 65536 rows
// Scan chunking: chunk = one wave's 64 rows in the GEMM
#define CC 128
#define LL 64

typedef unsigned short u16;
typedef __attribute__((ext_vector_type(8))) short short8;   // 8 bf16 = MFMA A/B frag
typedef __attribute__((ext_vector_type(4))) float f32x4;    // MFMA C/D frag

#define AS1(p) ((const __attribute__((address_space(1))) void*)(p))
#define AS3(p) ((__attribute__((address_space(3))) void*)(p))

__device__ __forceinline__ u16 f2bf_rtne(float f) {
    union { float f; unsigned u; } v; v.f = f;
    unsigned r = v.u + 0x7fffu + ((v.u >> 16) & 1u);
    return (u16)(r >> 16);
}
// pack two floats -> two bf16 (round-to-nearest): low16 = a, high16 = b
__device__ __forceinline__ unsigned pack2_rtn(float a, float b) {
    union { float f; unsigned u; } x, y; x.f = a; y.f = b;
    return ((x.u + 0x8000u) >> 16) | ((y.u + 0x8000u) & 0xffff0000u);
}

__device__ __forceinline__ float sp_fast(float z) {    // softplus
    return (z > 15.0f) ? z : __logf(1.0f + __expf(z));
}

__device__ __forceinline__ unsigned packFu(float F, float u) {
    __half2 h = __floats2half2_rn(F, u);
    return *reinterpret_cast<unsigned*>(&h);
}
__device__ __forceinline__ float2 unpackFu(unsigned v) {
    __half2 h = *reinterpret_cast<__half2*>(&v);
    return __half22float2(h);
}

__device__ __forceinline__ short8 packfrag(const float4& a, const float4& b) {
    uint4 t;
    t.x = pack2_rtn(a.x, a.y); t.y = pack2_rtn(a.z, a.w);
    t.z = pack2_rtn(b.x, b.y); t.w = pack2_rtn(b.z, b.w);
    return *reinterpret_cast<short8*>(&t);
}

// ---- W fp32 [3H,D] -> Wr bf16, laid out as 16 N-slices of 48 cols x 512 K,
// each slice = 3072 16B-units in DMA order with XOR bank-swizzle baked in.
// Logical (kc, r=col-in-slice, quad): unit-in-slice = kc*192 + ((4r+quad)^(r&7)).
// Col r = jn*16 + hl  ->  W row = jn*256 + nb*16 + hl;  k = kc*32 + quad*8.
__global__ __launch_bounds__(256) void convert_W(const float* __restrict__ W,
                                                 u16* __restrict__ Wr) {
    const int idx = blockIdx.x * 256 + threadIdx.x;   // 0..49151 (16B units)
    const int nb  = idx / 3072;
    const int rem = idx % 3072;
    const int kc  = rem / 192;
    const int v   = rem % 192;        // logical 4r+quad
    const int r   = v >> 2, quad = v & 3;
    const int jn = r >> 4, hl = r & 15;
    const int wrow = jn * HH + nb * 16 + hl;
    const int k0 = kc * 32 + quad * 8;
    const float4 v0 = *(const float4*)&W[(size_t)wrow * DD + k0];
    const float4 v1 = *(const float4*)&W[(size_t)wrow * DD + k0 + 4];
    u16 o[8];
    o[0]=f2bf_rtne(v0.x); o[1]=f2bf_rtne(v0.y); o[2]=f2bf_rtne(v0.z); o[3]=f2bf_rtne(v0.w);
    o[4]=f2bf_rtne(v1.x); o[5]=f2bf_rtne(v1.y); o[6]=f2bf_rtne(v1.z); o[7]=f2bf_rtne(v1.w);
    const int dst = nb * 3072 + kc * 192 + (v ^ (r & 7));
    *(uint4*)&Wr[(size_t)dst * 8] = *(const uint4*)o;
}

// ---- Fused MFMA GEMM + gates + chunk-scan, v6: persistent-B, zero K-loop sync.
// Block: 256 thr (4 waves), BN=48 cols (16 heads x 3 gates), BM=256 (wave owns
// 64 rows = one scan chunk). Whole 48-col x 512-K B-slice resident in LDS
// (48 KB, loaded once, ONE barrier). K-loop: 3 swizzled ds_reads + 12 MFMA +
// direct global x loads packed in-reg. Epilogue: gates -> packed fp16 Fu AND
// per-chunk (P,U) via shfl composition (pass1 fused away).
__global__ __launch_bounds__(256, 3) void gemm_gate_mfma(
    const float* __restrict__ x,      // [M,512] fp32
    const u16* __restrict__ Wr,       // sliced+swizzled bf16
    float* __restrict__ P_arr,        // [CC,BB,HH]
    float* __restrict__ U_arr,        // [CC,BB,HH]
    unsigned* __restrict__ Fu)        // d_out as [M,H] packed half2(F,u)
{
    __shared__ __align__(16) u16 Bs[24576];           // 48 KB: 16 kc x 192 units

    const int tid = threadIdx.x;
    const int nb   = blockIdx.x & 15;   // N-slice (16 heads)
    const int mblk = blockIdx.x >> 4;   // 256-row block
    const int w = tid >> 6;
    const int lane = tid & 63;
    const int l16 = lane & 15;
    const int quad = lane >> 4;
    const int m0w = mblk * 256 + w * 64;   // this wave's 64 rows = scan chunk

    // ---- B slice -> LDS via DMA (once) ----
    #pragma unroll
    for (int i = 0; i < 12; ++i) {
        const int u = i * 256 + tid;
        __builtin_amdgcn_global_load_lds(AS1(Wr + ((size_t)nb * 3072 + u) * 8),
                                         AS3(&Bs[u * 8]), 16, 0, 0);
    }

    // swizzled B read offsets (u16 index within a kc-tile)
    int boff[3];
    #pragma unroll
    for (int jn = 0; jn < 3; ++jn) {
        const int r = jn * 16 + l16;
        boff[jn] = ((4 * r + quad) ^ (r & 7)) * 8;
    }

    f32x4 acc[4][3];
    #pragma unroll
    for (int a = 0; a < 4; ++a)
        #pragma unroll
        for (int b = 0; b < 3; ++b)
            #pragma unroll
            for (int e = 0; e < 4; ++e) acc[a][b][e] = 0.0f;

    const float* xw = x + (size_t)m0w * DD;
    const int aoff = l16 * DD + quad * 8;

    // prefetch A(kc=0) raw fp32
    float4 ra[4][2];
    #pragma unroll
    for (int mf = 0; mf < 4; ++mf) {
        ra[mf][0] = *(const float4*)&xw[mf * 16 * DD + aoff];
        ra[mf][1] = *(const float4*)&xw[mf * 16 * DD + aoff + 4];
    }
    __syncthreads();   // drains B DMA (vmcnt) + joins waves; the ONLY barrier

    short8 afrA[4], afrB[4];
    #pragma unroll
    for (int mf = 0; mf < 4; ++mf) afrA[mf] = packfrag(ra[mf][0], ra[mf][1]);

    // ---- K loop: 16 steps, no barriers, no LDS writes ----
    #pragma unroll
    for (int kc = 0; kc < 16; ++kc) {
        if (kc < 15) {   // issue A(kc+1) loads early; latency hides under MFMA
            #pragma unroll
            for (int mf = 0; mf < 4; ++mf) {
                ra[mf][0] = *(const float4*)&xw[mf * 16 * DD + aoff + (kc + 1) * 32];
                ra[mf][1] = *(const float4*)&xw[mf * 16 * DD + aoff + (kc + 1) * 32 + 4];
            }
        }
        short8 bfr[3];
        #pragma unroll
        for (int jn = 0; jn < 3; ++jn)
            bfr[jn] = *(const short8*)&Bs[kc * 1536 + boff[jn]];

        __builtin_amdgcn_s_setprio(1);
        if ((kc & 1) == 0) {
            #pragma unroll
            for (int mf = 0; mf < 4; ++mf)
                #pragma unroll
                for (int jn = 0; jn < 3; ++jn)
                    acc[mf][jn] = __builtin_amdgcn_mfma_f32_16x16x32_bf16(
                        afrA[mf], bfr[jn], acc[mf][jn], 0, 0, 0);
        } else {
            #pragma unroll
            for (int mf = 0; mf < 4; ++mf)
                #pragma unroll
                for (int jn = 0; jn < 3; ++jn)
                    acc[mf][jn] = __builtin_amdgcn_mfma_f32_16x16x32_bf16(
                        afrB[mf], bfr[jn], acc[mf][jn], 0, 0, 0);
        }
        __builtin_amdgcn_s_setprio(0);

        if (kc < 15) {
            if ((kc & 1) == 0) {
                #pragma unroll
                for (int mf = 0; mf < 4; ++mf) afrB[mf] = packfrag(ra[mf][0], ra[mf][1]);
            } else {
                #pragma unroll
                for (int mf = 0; mf < 4; ++mf) afrA[mf] = packfrag(ra[mf][0], ra[mf][1]);
            }
        }
    }

    // ---- epilogue: gates -> packed Fu; fused chunk (P,U) over the 64 rows ----
    // t_local = mf*16 + quad*4 + r. Compose serial r, shfl across quads, serial mf.
    const int head = nb * 16 + l16;
    const int bI = m0w >> 13;            // batch
    const int cI = (m0w >> 6) & (CC - 1);  // chunk within batch
    float Pt = 1.0f, Ut = 0.0f;
    #pragma unroll
    for (int mf = 0; mf < 4; ++mf) {
        float Pseg = 1.0f, Useg = 0.0f;
        #pragma unroll
        for (int r = 0; r < 4; ++r) {
            const float fr = acc[mf][0][r];
            const float ir = acc[mf][1][r];
            const float hr = acc[mf][2][r];
            const float diff = sp_fast(-fr) - sp_fast(-ir);
            const float F = __builtin_amdgcn_rcpf(1.0f + __expf(diff));
            const float G = (hr >= 0.0f) ? (hr + 0.5f)
                                         : __builtin_amdgcn_rcpf(1.0f + __expf(-hr));
            const unsigned pw = packFu(F, (1.0f - F) * G);
            Fu[(size_t)(m0w + mf * 16 + quad * 4 + r) * HH + head] = pw;
            const float2 q = unpackFu(pw);   // fp16 roundtrip: match pass3 exactly
            Useg = q.x * Useg + q.y;
            Pseg *= q.x;
        }
        {   // merge quad pairs (0,1) and (2,3)
            const float Pp = __shfl_xor(Pseg, 16);
            const float Up = __shfl_xor(Useg, 16);
            const bool hi = (quad & 1);
            const float Plo = hi ? Pp : Pseg, Ulo = hi ? Up : Useg;
            const float Phi = hi ? Pseg : Pp, Uhi = hi ? Useg : Up;
            Pseg = Plo * Phi;  Useg = Phi * Ulo + Uhi;
        }
        {   // merge (01) with (23)
            const float Pp = __shfl_xor(Pseg, 32);
            const float Up = __shfl_xor(Useg, 32);
            const bool hi = (quad & 2);
            const float Plo = hi ? Pp : Pseg, Ulo = hi ? Up : Useg;
            const float Phi = hi ? Pseg : Pp, Uhi = hi ? Useg : Up;
            Pseg = Plo * Phi;  Useg = Phi * Ulo + Uhi;
        }
        Ut = Pseg * Ut + Useg;
        Pt *= Pseg;
    }
    if (quad == 0) {
        const size_t o = ((size_t)cI * BB + bI) * HH + head;
        P_arr[o] = Pt;
        U_arr[o] = Ut;
    }
}

// ---- Scan pass2: carry across CC=128 chunks per batch ----
__global__ __launch_bounds__(256) void scan_pass2(
    const float* __restrict__ h_prev, const float* __restrict__ P_arr,
    const float* __restrict__ U_arr, float* __restrict__ Hin) {
    const int b = blockIdx.x;
    const int h = threadIdx.x;
    const float z = h_prev[b * HH + h];
    float carry = (z >= 0.0f) ? (z + 0.5f) : __builtin_amdgcn_rcpf(1.0f + __expf(-z));
    #pragma unroll 8
    for (int c = 0; c < CC; ++c) {
        const size_t o = ((size_t)c * BB + b) * HH + h;
        Hin[o] = carry;
        carry = P_arr[o] * carry + U_arr[o];
    }
}

// ---- Scan pass3: in-place, reads packed (F,u), writes fp32 h ----
__global__ __launch_bounds__(256) void scan_pass3(
    const float* __restrict__ Hin, unsigned* buf) {
    const int pair = blockIdx.x * 2 + (threadIdx.x >> 7);
    const int b = pair / CC;
    const int c = pair % CC;
    const int h0 = (threadIdx.x & 127) * 2;
    float2 hv = *(const float2*)&Hin[((size_t)c * BB + b) * HH + h0];
    size_t base = ((size_t)(b * SS + c * LL)) * HH + h0;
    #pragma unroll 8
    for (int t = 0; t < LL; ++t) {
        const uint2 fu = *(const uint2*)&buf[base];
        const float2 a = unpackFu(fu.x);
        const float2 d = unpackFu(fu.y);
        hv.x = a.x * hv.x + a.y;
        hv.y = d.x * hv.y + d.y;
        *(float2*)&buf[base] = hv;   // same 8 bytes, now fp32 h
        base += HH;
    }
}

extern "C" void kernel_launch(void* const* d_in, const int* in_sizes, int n_in,
                              void* d_out, int out_size, void* d_ws, size_t ws_size,
                              hipStream_t stream) {
    const float* x      = (const float*)d_in[0];   // [B,S,D]
    const float* h_prev = (const float*)d_in[1];   // [B,H]
    const float* W      = (const float*)d_in[2];   // [3H,D]

    // Workspace: P | U | Hin (each CC*BB*HH f32 = 1 MB) | Wr bf16 (768 KB)
    float* P_arr = (float*)d_ws;
    float* U_arr = P_arr + (size_t)CC * BB * HH;
    float* Hin   = U_arr + (size_t)CC * BB * HH;
    u16*   Wr    = (u16*)(Hin + (size_t)CC * BB * HH);

    convert_W<<<192, 256, 0, stream>>>(W, Wr);
    gemm_gate_mfma<<<4096, 256, 0, stream>>>(x, Wr, P_arr, U_arr, (unsigned*)d_out);
    scan_pass2<<<BB, 256, 0, stream>>>(h_prev, P_arr, U_arr, Hin);
    scan_pass3<<<BB * CC / 2, 256, 0, stream>>>(Hin, (unsigned*)d_out);
}